// Round 1
// baseline (480.155 us; speedup 1.0000x reference)
//
#include <hip/hip_runtime.h>
#include <hip/hip_bf16.h>

#define PW 64
#define NV 512
#define HW 256
#define COV 16
#define BATCH 2048
#define XROW (PW * NV + COV)   // 32784
#define IMG 16384              // shorts per (pathway, k-block) staging image: 256 rows x 64 k

typedef short s16x8 __attribute__((ext_vector_type(8)));
typedef float f32x4 __attribute__((ext_vector_type(4)));

__device__ __forceinline__ unsigned short f2bf(float f) {
    union { float f; unsigned int u; } v;
    v.f = f;
    unsigned int u = v.u;
    unsigned int r = (u + 0x7fffu + ((u >> 16) & 1u)) >> 16;   // RNE
    return (unsigned short)r;
}

// packed f32x2 -> bf16x2 (v_cvt_pk_bf16_f32 on gfx950, RNE)
__device__ __forceinline__ unsigned int pack2(float a, float b) {
    __hip_bfloat162 h = __float22bfloat162_rn(float2{a, b});
    union { __hip_bfloat162 h; unsigned int u; } c;
    c.h = h;
    return c.u;
}

__device__ __forceinline__ float lrelu(float v) { return v >= 0.f ? v : 0.2f * v; }

// async global->LDS, 16 bytes per lane; LDS dest = wave-uniform base + lane*16
__device__ __forceinline__ void gl_lds16(const void* g, void* l) {
    __builtin_amdgcn_global_load_lds(
        (const __attribute__((address_space(1))) void*)g,
        (__attribute__((address_space(3))) void*)l, 16, 0, 0);
}

// ---------------------------------------------------------------------------
// Weight prep: fp32 [P][K][N] -> bf16 staging images, one 32 KB image per
// (pathway, 64-wide k-block):  image[n][slot][j] = W[kb*64 + (slot^(n&7))*8 + j][n]
// i.e. N-major transpose with the 16B-granule XOR swizzle PRE-APPLIED so the
// GEMM can global_load_lds it linearly and ds_read_b128 it conflict-free.
// W1: 64 p x 8 kb;  W2: 64 p x 4 kb.  768 blocks total.
// ---------------------------------------------------------------------------
__global__ __launch_bounds__(256)
void transpose_all(const float* __restrict__ W1, const float* __restrict__ W2,
                   unsigned short* __restrict__ W1I, unsigned short* __restrict__ W2I) {
    __shared__ float tile[64][260];    // 64 k-rows x 256 n, pad 4 floats
    int bx = blockIdx.x;
    const float* src;
    unsigned short* dst;
    if (bx < 512) {                    // W1 slab
        int p = bx >> 3, kb = bx & 7;
        src = W1 + ((size_t)p * NV + kb * 64) * HW;
        dst = W1I + (size_t)(p * 8 + kb) * IMG;
    } else {                           // W2 slab
        bx -= 512;
        int p = bx >> 2, kb = bx & 3;
        src = W2 + ((size_t)p * HW + kb * 64) * HW;
        dst = W2I + (size_t)(p * 4 + kb) * IMG;
    }
    const int t = threadIdx.x;
    #pragma unroll
    for (int i = 0; i < 16; ++i) {     // coalesced load of 64x256 f32 slab
        int idx = t + i * 256;         // float4 index 0..4095
        int r = idx >> 6, c4 = (idx & 63) << 2;
        *(float4*)&tile[r][c4] = *(const float4*)(src + (size_t)r * HW + c4);
    }
    __syncthreads();
    #pragma unroll
    for (int pass = 0; pass < 8; ++pass) {
        int idx = pass * 256 + t;      // output granule index 0..2047
        int n = idx >> 3, s = idx & 7;
        int g = s ^ (n & 7);           // slot s stores k-granule g
        unsigned short v[8];
        #pragma unroll
        for (int j = 0; j < 8; ++j)
            v[j] = f2bf(tile[g * 8 + j][n]);
        *(s16x8*)(dst + (size_t)idx * 8) = *(s16x8*)v;   // coalesced 16B stores
    }
}

// ---------------------------------------------------------------------------
// FULLY-FUSED pathway kernel (64-row tile x one pathway):
//   H1 = lrelu(x_p @ W1_p)   (LDS)    H2 = lrelu(H1 @ W2_p)  (regs)
//   pvec[p][row] = lrelu(H2 . W3_p)
// Changes this round:
//   * weights staged via global_load_lds (16B) from pre-swizzled images
//   * Bs LDS unpadded [256][64], ds_read slot = granule ^ (row&7)
//   * x-tile loads software-pipelined (issue next k-step during MFMA)
//   * XCD-aware block remap: each XCD owns 8 whole pathways (weights L2-fit)
// LDS = 9.2 + 32 + 33.8 + 1 = 76.8 KB -> 2 blocks/CU.
// ---------------------------------------------------------------------------
__global__ __launch_bounds__(256, 2)
void pathway_fused(const float* __restrict__ x, const unsigned short* __restrict__ W1I,
                   const unsigned short* __restrict__ W2I, const float* __restrict__ W3,
                   float* __restrict__ pvec) {
    __shared__ __align__(16) unsigned short As[64][72];      // x tile (bf16), padded
    __shared__ __align__(16) unsigned short Bs[256 * 64];    // weight k-slice, swizzled image
    __shared__ __align__(16) unsigned short H1t[64][264];    // full 64x256 H1 tile
    __shared__ float red[4][64];

    // XCD-aware remap: linear id -> (xcd, idx); each XCD gets pathways xcd*8..+8
    const int lin = blockIdx.x + blockIdx.y * (BATCH / 64);  // 0..2047
    const int xcd = lin & 7;
    const int idx0 = lin >> 3;                               // 0..255
    const int p   = xcd * 8 + (idx0 >> 5);                   // pathway
    const int bm0 = (idx0 & 31) * 64;                        // row tile

    const int t = threadIdx.x;
    const int lane = t & 63;
    const int wave = t >> 6;
    const int wn   = wave * 64;
    const int l15  = lane & 15;
    const int quad = lane >> 4;

    const float* Ap          = x   + (size_t)p * NV;
    const unsigned short* B1 = W1I + (size_t)p * 8 * IMG;
    const unsigned short* B2 = W2I + (size_t)p * 4 * IMG;

    // ---------------- stage A: H1 tile = lrelu(x @ W1) ----------------
    {
        float4 aReg[4];
        #pragma unroll
        for (int i = 0; i < 4; ++i) {            // prologue: x loads for k0=0
            int ii = t + i * 256, row = ii >> 4, c4 = (ii & 15) * 4;
            aReg[i] = *(const float4*)(Ap + (size_t)(bm0 + row) * XROW + c4);
        }
        f32x4 acc[4][4] = {};
        for (int k0 = 0; k0 < NV; k0 += 64) {
            #pragma unroll
            for (int i = 0; i < 4; ++i) {        // As: regs -> bf16 -> LDS
                int ii = t + i * 256, row = ii >> 4, c4 = (ii & 15) * 4;
                uint2 u;
                u.x = pack2(aReg[i].x, aReg[i].y);
                u.y = pack2(aReg[i].z, aReg[i].w);
                *(uint2*)&As[row][c4] = u;
            }
            {   // Bs: fire-and-forget async copy of the 32 KB swizzled image
                const unsigned short* img = B1 + (size_t)(k0 >> 6) * IMG;
                #pragma unroll
                for (int c = 0; c < 8; ++c) {
                    int off = wave * 8192 + c * 1024;        // bytes
                    gl_lds16((const char*)img + off + lane * 16, (char*)Bs + off);
                }
            }
            __syncthreads();                     // drains ds_writes + gl_lds
            if (k0 + 64 < NV) {                  // issue next x loads; latency
                #pragma unroll                   // hides under MFMA below
                for (int i = 0; i < 4; ++i) {
                    int ii = t + i * 256, row = ii >> 4, c4 = (ii & 15) * 4;
                    aReg[i] = *(const float4*)(Ap + (size_t)(bm0 + row) * XROW + k0 + 64 + c4);
                }
            }
            #pragma unroll
            for (int kk = 0; kk < 64; kk += 32) {
                s16x8 af[4], bfr[4];
                #pragma unroll
                for (int mi = 0; mi < 4; ++mi)
                    af[mi] = *(const s16x8*)&As[mi * 16 + l15][kk + quad * 8];
                #pragma unroll
                for (int ni = 0; ni < 4; ++ni) {
                    int row  = wn + ni * 16 + l15;
                    int slot = ((kk >> 3) + quad) ^ (row & 7);
                    bfr[ni] = *(const s16x8*)&Bs[row * 64 + slot * 8];
                }
                #pragma unroll
                for (int mi = 0; mi < 4; ++mi)
                    #pragma unroll
                    for (int ni = 0; ni < 4; ++ni)
                        acc[mi][ni] = __builtin_amdgcn_mfma_f32_16x16x32_bf16(
                            af[mi], bfr[ni], acc[mi][ni], 0, 0, 0);
            }
            __syncthreads();
        }
        // write lrelu(acc) into H1t (C/D layout: col=lane&15, row=quad*4+reg)
        #pragma unroll
        for (int mi = 0; mi < 4; ++mi)
            #pragma unroll
            for (int ni = 0; ni < 4; ++ni)
                #pragma unroll
                for (int r = 0; r < 4; ++r)
                    H1t[mi * 16 + quad * 4 + r][wn + ni * 16 + l15] =
                        f2bf(lrelu(acc[mi][ni][r]));
    }
    __syncthreads();

    // ---------------- stage B: H2 = lrelu(H1 @ W2), fused dot W3 ----------------
    f32x4 acc2[4][4] = {};
    for (int k0 = 0; k0 < HW; k0 += 64) {
        const unsigned short* img = B2 + (size_t)(k0 >> 6) * IMG;
        #pragma unroll
        for (int c = 0; c < 8; ++c) {
            int off = wave * 8192 + c * 1024;
            gl_lds16((const char*)img + off + lane * 16, (char*)Bs + off);
        }
        __syncthreads();
        #pragma unroll
        for (int kk = 0; kk < 64; kk += 32) {
            s16x8 af[4], bfr[4];
            #pragma unroll
            for (int mi = 0; mi < 4; ++mi)
                af[mi] = *(const s16x8*)&H1t[mi * 16 + l15][k0 + kk + quad * 8];
            #pragma unroll
            for (int ni = 0; ni < 4; ++ni) {
                int row  = wn + ni * 16 + l15;
                int slot = ((kk >> 3) + quad) ^ (row & 7);
                bfr[ni] = *(const s16x8*)&Bs[row * 64 + slot * 8];
            }
            #pragma unroll
            for (int mi = 0; mi < 4; ++mi)
                #pragma unroll
                for (int ni = 0; ni < 4; ++ni)
                    acc2[mi][ni] = __builtin_amdgcn_mfma_f32_16x16x32_bf16(
                        af[mi], bfr[ni], acc2[mi][ni], 0, 0, 0);
        }
        __syncthreads();
    }

    // dot with W3 over this wave's 64 cols (H2 stays f32 in registers)
    float w3v[4];
    #pragma unroll
    for (int ni = 0; ni < 4; ++ni)
        w3v[ni] = W3[(size_t)p * HW + wn + ni * 16 + l15];
    float part[4][4];
    #pragma unroll
    for (int mi = 0; mi < 4; ++mi) {
        #pragma unroll
        for (int r = 0; r < 4; ++r) {
            float s = 0.f;
            #pragma unroll
            for (int ni = 0; ni < 4; ++ni)
                s += lrelu(acc2[mi][ni][r]) * w3v[ni];
            part[mi][r] = s;
        }
    }
    #pragma unroll
    for (int off = 1; off < 16; off <<= 1)
        #pragma unroll
        for (int mi = 0; mi < 4; ++mi)
            #pragma unroll
            for (int r = 0; r < 4; ++r)
                part[mi][r] += __shfl_xor(part[mi][r], off);
    if (l15 == 0)
        #pragma unroll
        for (int mi = 0; mi < 4; ++mi)
            #pragma unroll
            for (int r = 0; r < 4; ++r)
                red[wave][mi * 16 + quad * 4 + r] = part[mi][r];
    __syncthreads();
    if (t < 64) {
        float s = red[0][t] + red[1][t] + red[2][t] + red[3][t];
        pvec[(size_t)p * BATCH + bm0 + t] = lrelu(s);
    }
}

// ---------------------------------------------------------------------------
// Per-pathway batch stats: mean, invstd, var.  64 blocks, one per pathway.
// stat layout: [0..63]=mean, [64..127]=invstd, [128..191]=var
// ---------------------------------------------------------------------------
__global__ __launch_bounds__(256)
void stats_k(const float* __restrict__ pvec, float* __restrict__ stat) {
    const int p = blockIdx.x;
    float s = 0.f, q = 0.f;
    for (int i = threadIdx.x; i < BATCH; i += 256) {
        float v = pvec[(size_t)p * BATCH + i];
        s += v; q += v * v;
    }
    #pragma unroll
    for (int off = 32; off; off >>= 1) {
        s += __shfl_down(s, off);
        q += __shfl_down(q, off);
    }
    __shared__ float ls[4], lq[4];
    const int wave = threadIdx.x >> 6, lane = threadIdx.x & 63;
    if (lane == 0) { ls[wave] = s; lq[wave] = q; }
    __syncthreads();
    if (threadIdx.x == 0) {
        float S = ls[0] + ls[1] + ls[2] + ls[3];
        float Q = lq[0] + lq[1] + lq[2] + lq[3];
        float mean = S * (1.f / BATCH);
        float var  = Q * (1.f / BATCH) - mean * mean;
        stat[p]       = mean;
        stat[64 + p]  = rsqrtf(var + 1e-5f);
        stat[128 + p] = var;
    }
}

// ---------------------------------------------------------------------------
// Final: closed-form global norm ||pn||^2 = sum_p B*(g^2*var/(var+eps)+beta^2),
// then batchnorm-apply, /norm, covariates, linear, sigmoid.
// ---------------------------------------------------------------------------
__global__ __launch_bounds__(256)
void final_k(const float* __restrict__ pvec, const float* __restrict__ stat,
             const float* __restrict__ gamma, const float* __restrict__ beta,
             const float* __restrict__ x, const float* __restrict__ fc_w,
             const float* __restrict__ fc_b, float* __restrict__ out) {
    const int b = blockIdx.x * 256 + threadIdx.x;
    float nsq = 0.f;
    #pragma unroll
    for (int p = 0; p < PW; ++p) {
        float g = gamma[p], bt = beta[p], var = stat[128 + p], inv = stat[64 + p];
        nsq += (float)BATCH * (g * g * var * inv * inv + bt * bt);
    }
    const float rn = rsqrtf(nsq);
    float acc = fc_b[0];
    #pragma unroll
    for (int p = 0; p < PW; ++p) {
        float pn = (pvec[(size_t)p * BATCH + b] - stat[p]) * stat[64 + p] * gamma[p] + beta[p];
        acc += pn * rn * fc_w[p];
    }
    #pragma unroll
    for (int c = 0; c < COV; ++c)
        acc += x[(size_t)b * XROW + PW * NV + c] * fc_w[PW + c];
    out[b] = 1.f / (1.f + __expf(-acc));
}

// ---------------------------------------------------------------------------
extern "C" void kernel_launch(void* const* d_in, const int* in_sizes, int n_in,
                              void* d_out, int out_size, void* d_ws, size_t ws_size,
                              hipStream_t stream) {
    const float* x     = (const float*)d_in[0];
    const float* W1    = (const float*)d_in[1];
    const float* W2    = (const float*)d_in[2];
    const float* W3    = (const float*)d_in[3];
    const float* gamma = (const float*)d_in[4];
    const float* beta  = (const float*)d_in[5];
    const float* fc_w  = (const float*)d_in[6];
    const float* fc_b  = (const float*)d_in[7];
    float* out = (float*)d_out;

    char* ws = (char*)d_ws;
    size_t off = 0;
    unsigned short* W1I = (unsigned short*)(ws + off); off += (size_t)PW * NV * HW * 2;  // 16.78 MB
    unsigned short* W2I = (unsigned short*)(ws + off); off += (size_t)PW * HW * HW * 2;  //  8.39 MB
    float* pvec = (float*)(ws + off); off += (size_t)PW * BATCH * 4;                      //  0.5 MB
    float* stat = (float*)(ws + off); off += 256 * 4;

    // 1) weight transpose + bf16 convert into swizzled staging images
    transpose_all<<<dim3(512 + 256), 256, 0, stream>>>(W1, W2, W1I, W2I);

    // 2) fully-fused pathway MLP: x -> pvec  (H1 in LDS, H2 in registers)
    pathway_fused<<<dim3(BATCH / 64, PW), 256, 0, stream>>>(x, W1I, W2I, W3, pvec);

    // 3) per-pathway stats (64 blocks)
    stats_k<<<PW, 256, 0, stream>>>(pvec, stat);

    // 4) final head (norm computed closed-form in-kernel)
    final_k<<<BATCH / 256, 256, 0, stream>>>(pvec, stat, gamma, beta, x, fc_w, fc_b, out);
}